// Round 1
// baseline (283.216 us; speedup 1.0000x reference)
//
#include <hip/hip_runtime.h>
#include <hip/hip_bf16.h>
#include <cstdint>
#include <cstddef>

#define Bn 8192
#define Dn 512
#define Sn 16

typedef __attribute__((ext_vector_type(4))) float f32x4;
typedef __attribute__((ext_vector_type(8))) __bf16 bf16x8;
typedef __attribute__((ext_vector_type(8))) short short8;

union BF8 { short8 s; __hip_bfloat16 h[8]; };

// ---------- prep: cast weights to bf16, compute A = -exp(A_log) ----------
__global__ __launch_bounds__(256) void prep_kernel(
    const float* __restrict__ w1, const float* __restrict__ v1,
    const float* __restrict__ dt, const float* __restrict__ w2,
    const float* __restrict__ Bp, const float* __restrict__ Cp,
    const float* __restrict__ Alog,
    __hip_bfloat16* __restrict__ w1b, __hip_bfloat16* __restrict__ v1b,
    __hip_bfloat16* __restrict__ dtb, __hip_bfloat16* __restrict__ w2b,
    __hip_bfloat16* __restrict__ bpcpb, float* __restrict__ A)
{
  int i = blockIdx.x*256 + threadIdx.x;
  if(i < Dn*Dn){
    w1b[i] = __float2bfloat16(w1[i]);
    v1b[i] = __float2bfloat16(v1[i]);
    dtb[i] = __float2bfloat16(dt[i]);
    w2b[i] = __float2bfloat16(w2[i]);
  }
  if(i < Sn*Dn){
    bpcpb[i]         = __float2bfloat16(Bp[i]);
    bpcpb[Sn*Dn + i] = __float2bfloat16(Cp[i]);
  }
  if(i < Dn*Sn){
    A[i] = -expf(Alog[i]);
  }
}

// ---------- LayerNorm: fp32 in -> bf16 out, one wave per row ----------
__global__ __launch_bounds__(256) void ln_kernel(
    const float* __restrict__ x, const float* __restrict__ g,
    const float* __restrict__ bta, __hip_bfloat16* __restrict__ xn)
{
  const int lane = threadIdx.x & 63;
  const int row  = blockIdx.x*4 + (threadIdx.x >> 6);
  const float* xr = x + (size_t)row*Dn;
  const int c = lane*8;
  f32x4 a0 = *(const f32x4*)(xr + c);
  f32x4 a1 = *(const f32x4*)(xr + c + 4);
  float s = 0.f, q = 0.f;
  #pragma unroll
  for(int j=0;j<4;j++){ s += a0[j]+a1[j]; q += a0[j]*a0[j] + a1[j]*a1[j]; }
  #pragma unroll
  for(int off=32; off; off >>= 1){ s += __shfl_xor(s, off); q += __shfl_xor(q, off); }
  const float mu = s * (1.f/Dn);
  const float rs = rsqrtf(q*(1.f/Dn) - mu*mu + 1e-5f);
  f32x4 g0 = *(const f32x4*)(g + c);
  f32x4 g1 = *(const f32x4*)(g + c + 4);
  f32x4 b0 = *(const f32x4*)(bta + c);
  f32x4 b1 = *(const f32x4*)(bta + c + 4);
  BF8 o;
  #pragma unroll
  for(int j=0;j<4;j++){
    o.h[j]   = __float2bfloat16((a0[j]-mu)*rs*g0[j] + b0[j]);
    o.h[4+j] = __float2bfloat16((a1[j]-mu)*rs*g1[j] + b1[j]);
  }
  *(short8*)(xn + (size_t)row*Dn + c) = o.s;
}

// ---------- generic MFMA GEMM: C[M,N] = act(X[M,K] @ W[N,K]^T + bias) ----------
// ACT: 0=none, 1=silu(y*convw_center), 2=silu(y), 3=softplus(y)
// OBF: true -> bf16 out, false -> fp32 out
template<int ACT, bool OBF>
__global__ __launch_bounds__(256) void gemm_kernel(
    const __hip_bfloat16* __restrict__ X,
    const __hip_bfloat16* __restrict__ W,
    const float* __restrict__ bias,
    const float* __restrict__ convw,
    void* __restrict__ outp, int M, int N, int K)
{
  const int lane = threadIdx.x & 63;
  const int wv   = threadIdx.x >> 6;
  const int r0 = blockIdx.y*128 + (wv>>1)*64;
  const int c0 = blockIdx.x*64  + (wv&1)*32;
  const int lr = lane & 15;
  const int lk = (lane >> 4) * 8;
  f32x4 acc[4][2] = {};
  for(int kk=0; kk<K; kk+=32){
    bf16x8 af[4], bf[2];
    #pragma unroll
    for(int m=0;m<4;m++)
      af[m] = *(const bf16x8*)(X + (size_t)(r0 + m*16 + lr)*K + kk + lk);
    #pragma unroll
    for(int n=0;n<2;n++)
      bf[n] = *(const bf16x8*)(W + (size_t)(c0 + n*16 + lr)*K + kk + lk);
    #pragma unroll
    for(int m=0;m<4;m++){
      #pragma unroll
      for(int n=0;n<2;n++)
        acc[m][n] = __builtin_amdgcn_mfma_f32_16x16x32_bf16(af[m], bf[n], acc[m][n], 0, 0, 0);
    }
  }
  const int er = (lane>>4)*4;
  const int ec = lane & 15;
  #pragma unroll
  for(int n=0;n<2;n++){
    const int cc = c0 + n*16 + ec;
    const float bv = bias[cc];
    const float cwv = (ACT==1) ? convw[cc*3+1] : 0.f;
    #pragma unroll
    for(int m=0;m<4;m++){
      #pragma unroll
      for(int j=0;j<4;j++){
        const int rr = r0 + m*16 + er + j;
        float y = acc[m][n][j] + bv;
        if(ACT==1){ float z = y*cwv; y = z/(1.f + __expf(-z)); }
        if(ACT==2){ y = y/(1.f + __expf(-y)); }
        if(ACT==3){ y = (y > 20.f) ? y : log1pf(__expf(y)); }
        if(OBF) ((__hip_bfloat16*)outp)[(size_t)rr*N + cc] = __float2bfloat16(y);
        else    ((float*)outp)[(size_t)rr*N + cc] = y;
      }
    }
  }
}

// ---------- small projection: Bm/Cm = x_conv @ [Bp;Cp]^T + bias ----------
__global__ __launch_bounds__(256) void bc_kernel(
    const __hip_bfloat16* __restrict__ xc,
    const __hip_bfloat16* __restrict__ bpcpb,
    const float* __restrict__ bpb, const float* __restrict__ cpb,
    float* __restrict__ BmCm)
{
  const int idx = blockIdx.x*256 + threadIdx.x;
  const int b = idx >> 5;
  const int n = idx & 31;
  const __hip_bfloat16* xr = xc + (size_t)b*Dn;
  const __hip_bfloat16* wr = bpcpb + (size_t)n*Dn;
  float s = (n < 16) ? bpb[n] : cpb[n-16];
  for(int k=0;k<Dn;k+=8){
    bf16x8 xv = *(const bf16x8*)(xr+k);
    bf16x8 wv = *(const bf16x8*)(wr+k);
    #pragma unroll
    for(int j=0;j<8;j++) s += (float)xv[j]*(float)wv[j];
  }
  BmCm[idx] = s;
}

// ---------- SSM elementwise: next_state + g = x_ssm*v ----------
__global__ __launch_bounds__(256) void ssm_kernel(
    const float* __restrict__ state,
    const float* __restrict__ delta,
    const __hip_bfloat16* __restrict__ xconv,
    const __hip_bfloat16* __restrict__ vbuf,
    const float* __restrict__ BmCm,
    const float* __restrict__ A,
    float* __restrict__ nstate,
    __hip_bfloat16* __restrict__ gbuf)
{
  const int b = blockIdx.x;
  const int tid = threadIdx.x;
  const int qlane = tid & 3;
  __shared__ float sB[16], sC[16];
  if(tid < 16) sB[tid] = BmCm[(size_t)b*32 + tid];
  else if(tid < 32) sC[tid-16] = BmCm[(size_t)b*32 + tid];
  __syncthreads();
  #pragma unroll
  for(int it=0; it<8; ++it){
    const int d = it*64 + (tid >> 2);
    const float dl = delta[(size_t)b*Dn + d];
    const float xc = __bfloat162float(xconv[(size_t)b*Dn + d]);
    const size_t off = ((size_t)b*Dn + d)*Sn + qlane*4;
    f32x4 st = *(const f32x4*)(state + off);
    f32x4 Av = *(const f32x4*)(A + d*Sn + qlane*4);
    f32x4 ns;
    float xs = 0.f;
    #pragma unroll
    for(int j=0;j<4;j++){
      const int s = qlane*4 + j;
      const float da = __expf(dl * Av[j]);
      const float nv = st[j]*da + dl*sB[s]*xc;
      ns[j] = nv;
      xs += nv * sC[s];
    }
    *(f32x4*)(nstate + off) = ns;
    xs += __shfl_xor(xs, 1);
    xs += __shfl_xor(xs, 2);
    if(qlane == 0){
      const float vv = __bfloat162float(vbuf[(size_t)b*Dn + d]);
      gbuf[(size_t)b*Dn + d] = __float2bfloat16(xs * vv);
    }
  }
}

extern "C" void kernel_launch(void* const* d_in, const int* in_sizes, int n_in,
                              void* d_out, int out_size, void* d_ws, size_t ws_size,
                              hipStream_t stream)
{
  const float* x      = (const float*)d_in[0];
  const float* sst    = (const float*)d_in[1];
  const float* ln_g   = (const float*)d_in[2];
  const float* ln_b   = (const float*)d_in[3];
  const float* w1_W   = (const float*)d_in[4];
  const float* w1_b   = (const float*)d_in[5];
  const float* v1_W   = (const float*)d_in[6];
  const float* v1_b   = (const float*)d_in[7];
  const float* w2_W   = (const float*)d_in[8];
  const float* w2_b   = (const float*)d_in[9];
  const float* conv_w = (const float*)d_in[10];
  const float* A_log  = (const float*)d_in[11];
  const float* Bp_W   = (const float*)d_in[12];
  const float* Bp_b   = (const float*)d_in[13];
  const float* Cp_W   = (const float*)d_in[14];
  const float* Cp_b   = (const float*)d_in[15];
  const float* dt_W   = (const float*)d_in[16];
  const float* dt_b   = (const float*)d_in[17];

  float* out    = (float*)d_out;
  float* nstate = out + (size_t)Bn*Dn;

  char* wsp = (char*)d_ws;
  auto alloc = [&](size_t bytes)->char*{
    char* p = wsp; wsp += (bytes + 255) & ~(size_t)255; return p;
  };
  __hip_bfloat16* xnorm = (__hip_bfloat16*)alloc((size_t)Bn*Dn*2);
  __hip_bfloat16* xconv = (__hip_bfloat16*)alloc((size_t)Bn*Dn*2);
  __hip_bfloat16* vbuf  = (__hip_bfloat16*)alloc((size_t)Bn*Dn*2);
  __hip_bfloat16* gbuf  = (__hip_bfloat16*)alloc((size_t)Bn*Dn*2);
  float*          delta = (float*)alloc((size_t)Bn*Dn*4);
  __hip_bfloat16* w1b   = (__hip_bfloat16*)alloc((size_t)Dn*Dn*2);
  __hip_bfloat16* v1b   = (__hip_bfloat16*)alloc((size_t)Dn*Dn*2);
  __hip_bfloat16* dtb   = (__hip_bfloat16*)alloc((size_t)Dn*Dn*2);
  __hip_bfloat16* w2b   = (__hip_bfloat16*)alloc((size_t)Dn*Dn*2);
  __hip_bfloat16* bpcpb = (__hip_bfloat16*)alloc((size_t)2*Sn*Dn*2);
  float*          BmCm  = (float*)alloc((size_t)Bn*32*4);
  float*          Abuf  = (float*)alloc((size_t)Dn*Sn*4);

  // 1. prep
  prep_kernel<<<dim3(Dn*Dn/256), dim3(256), 0, stream>>>(
      w1_W, v1_W, dt_W, w2_W, Bp_W, Cp_W, A_log, w1b, v1b, dtb, w2b, bpcpb, Abuf);
  // 2. layernorm
  ln_kernel<<<dim3(Bn/4), dim3(256), 0, stream>>>(x, ln_g, ln_b, xnorm);
  // 3. x_conv = silu((x_norm@w1^T + b) * cw)
  gemm_kernel<1,true><<<dim3(Dn/64, Bn/128), dim3(256), 0, stream>>>(
      xnorm, w1b, w1_b, conv_w, (void*)xconv, Bn, Dn, Dn);
  // 4. v = silu(x_norm@v1^T + b)
  gemm_kernel<2,true><<<dim3(Dn/64, Bn/128), dim3(256), 0, stream>>>(
      xnorm, v1b, v1_b, nullptr, (void*)vbuf, Bn, Dn, Dn);
  // 5. delta = softplus(x_conv@dt^T + b)  (fp32)
  gemm_kernel<3,false><<<dim3(Dn/64, Bn/128), dim3(256), 0, stream>>>(
      xconv, dtb, dt_b, nullptr, (void*)delta, Bn, Dn, Dn);
  // 6. Bm/Cm
  bc_kernel<<<dim3(Bn*32/256), dim3(256), 0, stream>>>(xconv, bpcpb, Bp_b, Cp_b, BmCm);
  // 7. SSM elementwise + g
  ssm_kernel<<<dim3(Bn), dim3(256), 0, stream>>>(
      sst, delta, xconv, vbuf, BmCm, Abuf, nstate, gbuf);
  // 8. out = g@w2^T + b (fp32)
  gemm_kernel<0,false><<<dim3(Dn/64, Bn/128), dim3(256), 0, stream>>>(
      gbuf, w2b, w2_b, nullptr, (void*)out, Bn, Dn, Dn);
}

// Round 2
// 225.531 us; speedup vs baseline: 1.2558x; 1.2558x over previous
//
#include <hip/hip_runtime.h>
#include <hip/hip_bf16.h>
#include <cstdint>
#include <cstddef>

#define Bn 8192
#define Dn 512
#define Sn 16

typedef __attribute__((ext_vector_type(4))) float f32x4;
typedef __attribute__((ext_vector_type(8))) __bf16 bf16x8;
typedef __attribute__((ext_vector_type(8))) short short8;

union BF8 { short8 s; __hip_bfloat16 h[8]; };

__device__ __forceinline__ void gload16(const void* gsrc, void* ldst){
  __builtin_amdgcn_global_load_lds(
      (const __attribute__((address_space(1))) void*)gsrc,
      (__attribute__((address_space(3))) void*)ldst, 16, 0, 0);
}

// ---------- prep: cast weights to bf16, compute A = -exp(A_log) ----------
__global__ __launch_bounds__(256) void prep_kernel(
    const float* __restrict__ w1, const float* __restrict__ v1,
    const float* __restrict__ dt, const float* __restrict__ w2,
    const float* __restrict__ Bp, const float* __restrict__ Cp,
    const float* __restrict__ Alog,
    __hip_bfloat16* __restrict__ w1b, __hip_bfloat16* __restrict__ v1b,
    __hip_bfloat16* __restrict__ dtb, __hip_bfloat16* __restrict__ w2b,
    __hip_bfloat16* __restrict__ bpcpb, float* __restrict__ A)
{
  int i = blockIdx.x*256 + threadIdx.x;
  if(i < Dn*Dn){
    w1b[i] = __float2bfloat16(w1[i]);
    v1b[i] = __float2bfloat16(v1[i]);
    dtb[i] = __float2bfloat16(dt[i]);
    w2b[i] = __float2bfloat16(w2[i]);
  }
  if(i < Sn*Dn){
    bpcpb[i]         = __float2bfloat16(Bp[i]);
    bpcpb[Sn*Dn + i] = __float2bfloat16(Cp[i]);
  }
  if(i < Dn*Sn){
    A[i] = -expf(Alog[i]);
  }
}

// ---------- LayerNorm: fp32 in -> bf16 out, one wave per row ----------
__global__ __launch_bounds__(256) void ln_kernel(
    const float* __restrict__ x, const float* __restrict__ g,
    const float* __restrict__ bta, __hip_bfloat16* __restrict__ xn)
{
  const int lane = threadIdx.x & 63;
  const int row  = blockIdx.x*4 + (threadIdx.x >> 6);
  const float* xr = x + (size_t)row*Dn;
  const int c = lane*8;
  f32x4 a0 = *(const f32x4*)(xr + c);
  f32x4 a1 = *(const f32x4*)(xr + c + 4);
  float s = 0.f, q = 0.f;
  #pragma unroll
  for(int j=0;j<4;j++){ s += a0[j]+a1[j]; q += a0[j]*a0[j] + a1[j]*a1[j]; }
  #pragma unroll
  for(int off=32; off; off >>= 1){ s += __shfl_xor(s, off); q += __shfl_xor(q, off); }
  const float mu = s * (1.f/Dn);
  const float rs = rsqrtf(q*(1.f/Dn) - mu*mu + 1e-5f);
  f32x4 g0 = *(const f32x4*)(g + c);
  f32x4 g1 = *(const f32x4*)(g + c + 4);
  f32x4 b0 = *(const f32x4*)(bta + c);
  f32x4 b1 = *(const f32x4*)(bta + c + 4);
  BF8 o;
  #pragma unroll
  for(int j=0;j<4;j++){
    o.h[j]   = __float2bfloat16((a0[j]-mu)*rs*g0[j] + b0[j]);
    o.h[4+j] = __float2bfloat16((a1[j]-mu)*rs*g1[j] + b1[j]);
  }
  *(short8*)(xn + (size_t)row*Dn + c) = o.s;
}

// ---------- tiled MFMA GEMM with global_load_lds + XOR-swizzled LDS ----------
// C[M,N] = act(X[M,K] @ W[N,K]^T + bias); optional dual W for shared-A fusion.
// Tile: BM=128, BN=64, BK=64, 256 threads (4 waves, each 64x32 output).
// ACT: 0=none, 1=silu(y*convw_center), 2=silu(y), 3=softplus(y)
template<int ACT1, int ACT2, bool DUAL, bool OBF>
__global__ __launch_bounds__(256) void tgemm_kernel(
    const __hip_bfloat16* __restrict__ X,
    const __hip_bfloat16* __restrict__ W1,
    const __hip_bfloat16* __restrict__ W2,
    const float* __restrict__ bias1,
    const float* __restrict__ bias2,
    const float* __restrict__ convw,
    void* __restrict__ out1, void* __restrict__ out2,
    int M, int N, int K)
{
  __shared__ char smem[32768] __attribute__((aligned(128)));
  const int tid  = threadIdx.x;
  const int wv   = tid >> 6;
  const int lane = tid & 63;
  const int r0 = blockIdx.y * 128;
  const int c0 = blockIdx.x * 64;

  f32x4 acc1[4][2] = {};
  f32x4 acc2[4][2] = {};

  const int lr = lane & 15;
  const int lg = lane >> 4;

  for(int kk = 0; kk < K; kk += 64){
    // ---- stage A-tile [128 rows][64 k] = 16KB, linear LDS dest,
    //      pre-swizzled global source: LDS slot (row, c) <- global chunk c^(row&7)
    #pragma unroll
    for(int i=0;i<4;i++){
      const int o   = i*4096 + tid*16;
      const int row = o >> 7;
      const int g   = ((o>>4)&7) ^ (row&7);
      gload16(X + (size_t)(r0+row)*K + kk + g*8, smem + i*4096 + (wv<<10));
    }
    // ---- stage B-tile(s) [64 cols][64 k] = 8KB each
    #pragma unroll
    for(int i=0;i<2;i++){
      const int o   = i*4096 + tid*16;
      const int row = o >> 7;
      const int g   = ((o>>4)&7) ^ (row&7);
      gload16(W1 + (size_t)(c0+row)*K + kk + g*8, smem + 16384 + i*4096 + (wv<<10));
      if(DUAL)
        gload16(W2 + (size_t)(c0+row)*K + kk + g*8, smem + 24576 + i*4096 + (wv<<10));
    }
    __syncthreads();   // drains vmcnt -> LDS tile complete

    bf16x8 af[4][2], b1f[2][2], b2f[2][2];
    #pragma unroll
    for(int m=0;m<4;m++){
      #pragma unroll
      for(int k2=0;k2<2;k2++){
        const int r = (wv>>1)*64 + m*16 + lr;
        const int c = (k2*4 + lg) ^ (r&7);
        af[m][k2] = *(const bf16x8*)(smem + r*128 + c*16);
      }
    }
    #pragma unroll
    for(int n=0;n<2;n++){
      #pragma unroll
      for(int k2=0;k2<2;k2++){
        const int r = (wv&1)*32 + n*16 + lr;
        const int c = (k2*4 + lg) ^ (r&7);
        b1f[n][k2] = *(const bf16x8*)(smem + 16384 + r*128 + c*16);
        if(DUAL)
          b2f[n][k2] = *(const bf16x8*)(smem + 24576 + r*128 + c*16);
      }
    }
    #pragma unroll
    for(int k2=0;k2<2;k2++){
      #pragma unroll
      for(int m=0;m<4;m++){
        #pragma unroll
        for(int n=0;n<2;n++){
          acc1[m][n] = __builtin_amdgcn_mfma_f32_16x16x32_bf16(af[m][k2], b1f[n][k2], acc1[m][n], 0, 0, 0);
          if(DUAL)
            acc2[m][n] = __builtin_amdgcn_mfma_f32_16x16x32_bf16(af[m][k2], b2f[n][k2], acc2[m][n], 0, 0, 0);
        }
      }
    }
    __syncthreads();
  }

  // ---- epilogue
  const int er = lg*4;
  const int ec = lr;
  #pragma unroll
  for(int n=0;n<2;n++){
    const int cc = c0 + (wv&1)*32 + n*16 + ec;
    const float bv1 = bias1[cc];
    const float cwv = (ACT1==1) ? convw[cc*3+1] : 0.f;
    const float bv2 = DUAL ? bias2[cc] : 0.f;
    #pragma unroll
    for(int m=0;m<4;m++){
      #pragma unroll
      for(int j=0;j<4;j++){
        const int rr = r0 + (wv>>1)*64 + m*16 + er + j;
        float y = acc1[m][n][j] + bv1;
        if(ACT1==1){ float z = y*cwv; y = z/(1.f + __expf(-z)); }
        if(ACT1==2){ y = y/(1.f + __expf(-y)); }
        if(ACT1==3){ y = (y > 20.f) ? y : log1pf(__expf(y)); }
        if(OBF) ((__hip_bfloat16*)out1)[(size_t)rr*N + cc] = __float2bfloat16(y);
        else    ((float*)out1)[(size_t)rr*N + cc] = y;
        if(DUAL){
          float y2 = acc2[m][n][j] + bv2;
          if(ACT2==1){ float z = y2*cwv; y2 = z/(1.f + __expf(-z)); }
          if(ACT2==2){ y2 = y2/(1.f + __expf(-y2)); }
          if(ACT2==3){ y2 = (y2 > 20.f) ? y2 : log1pf(__expf(y2)); }
          if(OBF) ((__hip_bfloat16*)out2)[(size_t)rr*N + cc] = __float2bfloat16(y2);
          else    ((float*)out2)[(size_t)rr*N + cc] = y2;
        }
      }
    }
  }
}

// ---------- small projection: Bm/Cm = x_conv @ [Bp;Cp]^T + bias ----------
__global__ __launch_bounds__(256) void bc_kernel(
    const __hip_bfloat16* __restrict__ xc,
    const __hip_bfloat16* __restrict__ bpcpb,
    const float* __restrict__ bpb, const float* __restrict__ cpb,
    float* __restrict__ BmCm)
{
  const int idx = blockIdx.x*256 + threadIdx.x;
  const int b = idx >> 5;
  const int n = idx & 31;
  const __hip_bfloat16* xr = xc + (size_t)b*Dn;
  const __hip_bfloat16* wr = bpcpb + (size_t)n*Dn;
  float s = (n < 16) ? bpb[n] : cpb[n-16];
  for(int k=0;k<Dn;k+=8){
    bf16x8 xv = *(const bf16x8*)(xr+k);
    bf16x8 wv = *(const bf16x8*)(wr+k);
    #pragma unroll
    for(int j=0;j<8;j++) s += (float)xv[j]*(float)wv[j];
  }
  BmCm[idx] = s;
}

// ---------- SSM elementwise: next_state + g = x_ssm*v ----------
__global__ __launch_bounds__(256) void ssm_kernel(
    const float* __restrict__ state,
    const float* __restrict__ delta,
    const __hip_bfloat16* __restrict__ xconv,
    const __hip_bfloat16* __restrict__ vbuf,
    const float* __restrict__ BmCm,
    const float* __restrict__ A,
    float* __restrict__ nstate,
    __hip_bfloat16* __restrict__ gbuf)
{
  const int b = blockIdx.x;
  const int tid = threadIdx.x;
  const int qlane = tid & 3;
  __shared__ float sB[16], sC[16];
  if(tid < 16) sB[tid] = BmCm[(size_t)b*32 + tid];
  else if(tid < 32) sC[tid-16] = BmCm[(size_t)b*32 + tid];
  __syncthreads();
  #pragma unroll
  for(int it=0; it<8; ++it){
    const int d = it*64 + (tid >> 2);
    const float dl = delta[(size_t)b*Dn + d];
    const float xc = __bfloat162float(xconv[(size_t)b*Dn + d]);
    const size_t off = ((size_t)b*Dn + d)*Sn + qlane*4;
    f32x4 st = *(const f32x4*)(state + off);
    f32x4 Av = *(const f32x4*)(A + d*Sn + qlane*4);
    f32x4 ns;
    float xs = 0.f;
    #pragma unroll
    for(int j=0;j<4;j++){
      const int s = qlane*4 + j;
      const float da = __expf(dl * Av[j]);
      const float nv = st[j]*da + dl*sB[s]*xc;
      ns[j] = nv;
      xs += nv * sC[s];
    }
    *(f32x4*)(nstate + off) = ns;
    xs += __shfl_xor(xs, 1);
    xs += __shfl_xor(xs, 2);
    if(qlane == 0){
      const float vv = __bfloat162float(vbuf[(size_t)b*Dn + d]);
      gbuf[(size_t)b*Dn + d] = __float2bfloat16(xs * vv);
    }
  }
}

extern "C" void kernel_launch(void* const* d_in, const int* in_sizes, int n_in,
                              void* d_out, int out_size, void* d_ws, size_t ws_size,
                              hipStream_t stream)
{
  const float* x      = (const float*)d_in[0];
  const float* sst    = (const float*)d_in[1];
  const float* ln_g   = (const float*)d_in[2];
  const float* ln_b   = (const float*)d_in[3];
  const float* w1_W   = (const float*)d_in[4];
  const float* w1_b   = (const float*)d_in[5];
  const float* v1_W   = (const float*)d_in[6];
  const float* v1_b   = (const float*)d_in[7];
  const float* w2_W   = (const float*)d_in[8];
  const float* w2_b   = (const float*)d_in[9];
  const float* conv_w = (const float*)d_in[10];
  const float* A_log  = (const float*)d_in[11];
  const float* Bp_W   = (const float*)d_in[12];
  const float* Bp_b   = (const float*)d_in[13];
  const float* Cp_W   = (const float*)d_in[14];
  const float* Cp_b   = (const float*)d_in[15];
  const float* dt_W   = (const float*)d_in[16];
  const float* dt_b   = (const float*)d_in[17];

  float* out    = (float*)d_out;
  float* nstate = out + (size_t)Bn*Dn;

  char* wsp = (char*)d_ws;
  auto alloc = [&](size_t bytes)->char*{
    char* p = wsp; wsp += (bytes + 255) & ~(size_t)255; return p;
  };
  __hip_bfloat16* xnorm = (__hip_bfloat16*)alloc((size_t)Bn*Dn*2);
  __hip_bfloat16* xconv = (__hip_bfloat16*)alloc((size_t)Bn*Dn*2);
  __hip_bfloat16* vbuf  = (__hip_bfloat16*)alloc((size_t)Bn*Dn*2);
  __hip_bfloat16* gbuf  = (__hip_bfloat16*)alloc((size_t)Bn*Dn*2);
  float*          delta = (float*)alloc((size_t)Bn*Dn*4);
  __hip_bfloat16* w1b   = (__hip_bfloat16*)alloc((size_t)Dn*Dn*2);
  __hip_bfloat16* v1b   = (__hip_bfloat16*)alloc((size_t)Dn*Dn*2);
  __hip_bfloat16* dtb   = (__hip_bfloat16*)alloc((size_t)Dn*Dn*2);
  __hip_bfloat16* w2b   = (__hip_bfloat16*)alloc((size_t)Dn*Dn*2);
  __hip_bfloat16* bpcpb = (__hip_bfloat16*)alloc((size_t)2*Sn*Dn*2);
  float*          BmCm  = (float*)alloc((size_t)Bn*32*4);
  float*          Abuf  = (float*)alloc((size_t)Dn*Sn*4);

  // 1. prep
  prep_kernel<<<dim3(Dn*Dn/256), dim3(256), 0, stream>>>(
      w1_W, v1_W, dt_W, w2_W, Bp_W, Cp_W, A_log, w1b, v1b, dtb, w2b, bpcpb, Abuf);
  // 2. layernorm
  ln_kernel<<<dim3(Bn/4), dim3(256), 0, stream>>>(x, ln_g, ln_b, xnorm);
  // 3+4. fused: x_conv = silu((x_norm@w1^T + b)*cw), v = silu(x_norm@v1^T + b)
  tgemm_kernel<1,2,true,true><<<dim3(Dn/64, Bn/128), dim3(256), 0, stream>>>(
      xnorm, w1b, v1b, w1_b, v1_b, conv_w, (void*)xconv, (void*)vbuf, Bn, Dn, Dn);
  // 5. delta = softplus(x_conv@dt^T + b)  (fp32)
  tgemm_kernel<3,0,false,false><<<dim3(Dn/64, Bn/128), dim3(256), 0, stream>>>(
      xconv, dtb, nullptr, dt_b, nullptr, nullptr, (void*)delta, nullptr, Bn, Dn, Dn);
  // 6. Bm/Cm
  bc_kernel<<<dim3(Bn*32/256), dim3(256), 0, stream>>>(xconv, bpcpb, Bp_b, Cp_b, BmCm);
  // 7. SSM elementwise + g
  ssm_kernel<<<dim3(Bn), dim3(256), 0, stream>>>(
      sst, delta, xconv, vbuf, BmCm, Abuf, nstate, gbuf);
  // 8. out = g@w2^T + b (fp32)
  tgemm_kernel<0,0,false,false><<<dim3(Dn/64, Bn/128), dim3(256), 0, stream>>>(
      gbuf, w2b, nullptr, w2_b, nullptr, nullptr, (void*)out, nullptr, Bn, Dn, Dn);
}

// Round 3
// 185.708 us; speedup vs baseline: 1.5251x; 1.2144x over previous
//
#include <hip/hip_runtime.h>
#include <hip/hip_bf16.h>
#include <cstdint>
#include <cstddef>

#define Bn 8192
#define Dn 512
#define Sn 16

typedef __attribute__((ext_vector_type(4))) float f32x4;
typedef __attribute__((ext_vector_type(8))) __bf16 bf16x8;
typedef __attribute__((ext_vector_type(8))) short short8;

union BF8 { short8 s; __hip_bfloat16 h[8]; };

__device__ __forceinline__ void gload16(const void* gsrc, void* ldst){
  __builtin_amdgcn_global_load_lds(
      (const __attribute__((address_space(1))) void*)gsrc,
      (__attribute__((address_space(3))) void*)ldst, 16, 0, 0);
}

// ---------- prep: cast weights to bf16, compute A = -exp(A_log) ----------
__global__ __launch_bounds__(256) void prep_kernel(
    const float* __restrict__ w1, const float* __restrict__ v1,
    const float* __restrict__ dt, const float* __restrict__ w2,
    const float* __restrict__ Bp, const float* __restrict__ Cp,
    const float* __restrict__ Alog,
    __hip_bfloat16* __restrict__ w1b, __hip_bfloat16* __restrict__ v1b,
    __hip_bfloat16* __restrict__ dtb, __hip_bfloat16* __restrict__ w2b,
    __hip_bfloat16* __restrict__ bpcpb, float* __restrict__ A)
{
  int i = blockIdx.x*256 + threadIdx.x;
  if(i < Dn*Dn){
    w1b[i] = __float2bfloat16(w1[i]);
    v1b[i] = __float2bfloat16(v1[i]);
    dtb[i] = __float2bfloat16(dt[i]);
    w2b[i] = __float2bfloat16(w2[i]);
  }
  if(i < Sn*Dn){
    bpcpb[i]         = __float2bfloat16(Bp[i]);
    bpcpb[Sn*Dn + i] = __float2bfloat16(Cp[i]);
  }
  if(i < Dn*Sn){
    A[i] = -expf(Alog[i]);
  }
}

// ---------- LayerNorm: fp32 in -> bf16 out, one wave per row ----------
__global__ __launch_bounds__(256) void ln_kernel(
    const float* __restrict__ x, const float* __restrict__ g,
    const float* __restrict__ bta, __hip_bfloat16* __restrict__ xn)
{
  const int lane = threadIdx.x & 63;
  const int row  = blockIdx.x*4 + (threadIdx.x >> 6);
  const float* xr = x + (size_t)row*Dn;
  const int c = lane*8;
  f32x4 a0 = *(const f32x4*)(xr + c);
  f32x4 a1 = *(const f32x4*)(xr + c + 4);
  float s = 0.f, q = 0.f;
  #pragma unroll
  for(int j=0;j<4;j++){ s += a0[j]+a1[j]; q += a0[j]*a0[j] + a1[j]*a1[j]; }
  #pragma unroll
  for(int off=32; off; off >>= 1){ s += __shfl_xor(s, off); q += __shfl_xor(q, off); }
  const float mu = s * (1.f/Dn);
  const float rs = rsqrtf(q*(1.f/Dn) - mu*mu + 1e-5f);
  f32x4 g0 = *(const f32x4*)(g + c);
  f32x4 g1 = *(const f32x4*)(g + c + 4);
  f32x4 b0 = *(const f32x4*)(bta + c);
  f32x4 b1 = *(const f32x4*)(bta + c + 4);
  BF8 o;
  #pragma unroll
  for(int j=0;j<4;j++){
    o.h[j]   = __float2bfloat16((a0[j]-mu)*rs*g0[j] + b0[j]);
    o.h[4+j] = __float2bfloat16((a1[j]-mu)*rs*g1[j] + b1[j]);
  }
  *(short8*)(xn + (size_t)row*Dn + c) = o.s;
}

// ---------- tiled MFMA GEMM, 2-phase pipelined (T3 minimum template) ----------
// C[M,N] = act(X[M,K] @ W[N,K]^T + bias)
// DUAL: second weight W2 sharing the A-tile (w1+v1 fusion)
// BC:   third tiny weight W3 [32,K] computed by blockIdx.x==0 only (Bm/Cm fusion)
// Tile: BM=128, BN=64, BK=64, 256 threads. Double-buffered LDS, counted vmcnt.
// ACT: 0=none, 1=silu(y*convw_center), 2=silu(y), 3=softplus(y)
template<int ACT1, int ACT2, bool DUAL, bool BC, bool OBF>
__global__ __launch_bounds__(256) void tgemm_kernel(
    const __hip_bfloat16* __restrict__ X,
    const __hip_bfloat16* __restrict__ W1,
    const __hip_bfloat16* __restrict__ W2,
    const __hip_bfloat16* __restrict__ W3,
    const float* __restrict__ bias1,
    const float* __restrict__ bias2,
    const float* __restrict__ bpb,
    const float* __restrict__ cpb,
    const float* __restrict__ convw,
    void* __restrict__ out1, void* __restrict__ out2,
    float* __restrict__ out3,
    int M, int N, int K)
{
  constexpr int B1OFF = 32768;
  constexpr int B2OFF = 49152;
  constexpr int B3OFF = DUAL ? 65536 : 49152;
  constexpr int SMB   = B3OFF + (BC ? 8192 : 0) + (DUAL && !BC ? 16384 : 0);
  // DUAL: A 2x16K + B1 2x8K + B2 2x8K = 64K ; single: 48K ; +BC: +8K
  __shared__ char smem[(SMB > 65536) ? SMB : (DUAL ? 65536 : (BC ? 57344 : 49152))] __attribute__((aligned(128)));

  const int tid  = threadIdx.x;
  const int wv   = tid >> 6;
  const int lane = tid & 63;
  const int r0 = blockIdx.y * 128;
  const int c0 = blockIdx.x * 64;
  const bool doBC = BC && (blockIdx.x == 0);

  f32x4 acc1[4][2] = {};
  f32x4 acc2[4][2] = {};
  f32x4 acc3[4]    = {};

  const int lr = lane & 15;
  const int lg = lane >> 4;

  auto stage = [&](int buf, int kk){
    #pragma unroll
    for(int i=0;i<4;i++){
      const int o   = i*4096 + tid*16;
      const int row = o >> 7;
      const int g   = ((o>>4)&7) ^ (row&7);
      gload16(X + (size_t)(r0+row)*K + kk + g*8, smem + buf*16384 + i*4096 + (wv<<10));
    }
    #pragma unroll
    for(int i=0;i<2;i++){
      const int o   = i*4096 + tid*16;
      const int row = o >> 7;
      const int g   = ((o>>4)&7) ^ (row&7);
      gload16(W1 + (size_t)(c0+row)*K + kk + g*8, smem + B1OFF + buf*8192 + i*4096 + (wv<<10));
      if(DUAL)
        gload16(W2 + (size_t)(c0+row)*K + kk + g*8, smem + B2OFF + buf*8192 + i*4096 + (wv<<10));
    }
    if(BC){ if(doBC){
      const int o   = tid*16;
      const int row = o >> 7;
      const int g   = ((o>>4)&7) ^ (row&7);
      gload16(W3 + (size_t)row*K + kk + g*8, smem + B3OFF + buf*4096 + (wv<<10));
    }}
  };

  const int NT = K >> 6;
  stage(0, 0);
  for(int t=0; t<NT; ++t){
    const int cur = t & 1;
    if(t+1 < NT){
      stage(cur^1, (t+1)<<6);
      // wait only the PREVIOUS tile's loads (FIFO): outstanding <= loads-just-issued
      if constexpr (DUAL){
        asm volatile("s_waitcnt vmcnt(8)" ::: "memory");
      } else if constexpr (BC){
        if(doBC) asm volatile("s_waitcnt vmcnt(7)" ::: "memory");
        else     asm volatile("s_waitcnt vmcnt(6)" ::: "memory");
      } else {
        asm volatile("s_waitcnt vmcnt(6)" ::: "memory");
      }
    } else {
      asm volatile("s_waitcnt vmcnt(0)" ::: "memory");
    }
    __builtin_amdgcn_s_barrier();

    const char* bufA = smem + cur*16384;
    const char* buf1 = smem + B1OFF + cur*8192;
    const char* buf2 = smem + B2OFF + cur*8192;
    const char* buf3 = smem + B3OFF + cur*4096;

    bf16x8 af[4][2], b1f[2][2], b2f[2][2], b3f[2];
    #pragma unroll
    for(int m=0;m<4;m++){
      #pragma unroll
      for(int k2=0;k2<2;k2++){
        const int r = (wv>>1)*64 + m*16 + lr;
        const int c = (k2*4 + lg) ^ (r&7);
        af[m][k2] = *(const bf16x8*)(bufA + r*128 + c*16);
      }
    }
    #pragma unroll
    for(int n=0;n<2;n++){
      #pragma unroll
      for(int k2=0;k2<2;k2++){
        const int r = (wv&1)*32 + n*16 + lr;
        const int c = (k2*4 + lg) ^ (r&7);
        b1f[n][k2] = *(const bf16x8*)(buf1 + r*128 + c*16);
        if(DUAL)
          b2f[n][k2] = *(const bf16x8*)(buf2 + r*128 + c*16);
      }
    }
    if(BC){ if(doBC){
      #pragma unroll
      for(int k2=0;k2<2;k2++){
        const int r = (wv&1)*16 + lr;
        const int c = (k2*4 + lg) ^ (r&7);
        b3f[k2] = *(const bf16x8*)(buf3 + r*128 + c*16);
      }
    }}

    #pragma unroll
    for(int k2=0;k2<2;k2++){
      #pragma unroll
      for(int m=0;m<4;m++){
        #pragma unroll
        for(int n=0;n<2;n++){
          acc1[m][n] = __builtin_amdgcn_mfma_f32_16x16x32_bf16(af[m][k2], b1f[n][k2], acc1[m][n], 0, 0, 0);
          if(DUAL)
            acc2[m][n] = __builtin_amdgcn_mfma_f32_16x16x32_bf16(af[m][k2], b2f[n][k2], acc2[m][n], 0, 0, 0);
        }
        if(BC){ if(doBC){
          acc3[m] = __builtin_amdgcn_mfma_f32_16x16x32_bf16(af[m][k2], b3f[k2], acc3[m], 0, 0, 0);
        }}
      }
    }
  }
  // buffers fully drained by the last vmcnt(0)+barrier; epilogue is reg+global only

  const int er = lg*4;
  const int ec = lr;
  #pragma unroll
  for(int n=0;n<2;n++){
    const int cc = c0 + (wv&1)*32 + n*16 + ec;
    const float bv1 = bias1[cc];
    const float cwv = (ACT1==1) ? convw[cc*3+1] : 0.f;
    const float bv2 = DUAL ? bias2[cc] : 0.f;
    #pragma unroll
    for(int m=0;m<4;m++){
      #pragma unroll
      for(int j=0;j<4;j++){
        const int rr = r0 + (wv>>1)*64 + m*16 + er + j;
        float y = acc1[m][n][j] + bv1;
        if(ACT1==1){ float z = y*cwv; y = z/(1.f + __expf(-z)); }
        if(ACT1==2){ y = y/(1.f + __expf(-y)); }
        if(ACT1==3){ y = (y > 20.f) ? y : log1pf(__expf(y)); }
        if(OBF) ((__hip_bfloat16*)out1)[(size_t)rr*N + cc] = __float2bfloat16(y);
        else    ((float*)out1)[(size_t)rr*N + cc] = y;
        if(DUAL){
          float y2 = acc2[m][n][j] + bv2;
          if(ACT2==1){ float z = y2*cwv; y2 = z/(1.f + __expf(-z)); }
          if(ACT2==2){ y2 = y2/(1.f + __expf(-y2)); }
          if(ACT2==3){ y2 = (y2 > 20.f) ? y2 : log1pf(__expf(y2)); }
          if(OBF) ((__hip_bfloat16*)out2)[(size_t)rr*N + cc] = __float2bfloat16(y2);
          else    ((float*)out2)[(size_t)rr*N + cc] = y2;
        }
      }
    }
  }
  if(BC){ if(doBC){
    const int cc3 = (wv&1)*16 + ec;
    const float bv3 = (cc3 < 16) ? bpb[cc3] : cpb[cc3-16];
    #pragma unroll
    for(int m=0;m<4;m++){
      #pragma unroll
      for(int j=0;j<4;j++){
        const int rr = r0 + (wv>>1)*64 + m*16 + er + j;
        out3[(size_t)rr*32 + cc3] = acc3[m][j] + bv3;
      }
    }
  }}
}

// ---------- SSM elementwise: next_state + g = x_ssm*v ----------
__global__ __launch_bounds__(256) void ssm_kernel(
    const float* __restrict__ state,
    const float* __restrict__ delta,
    const __hip_bfloat16* __restrict__ xconv,
    const __hip_bfloat16* __restrict__ vbuf,
    const float* __restrict__ BmCm,
    const float* __restrict__ A,
    float* __restrict__ nstate,
    __hip_bfloat16* __restrict__ gbuf)
{
  const int b = blockIdx.x;
  const int tid = threadIdx.x;
  const int qlane = tid & 3;
  __shared__ float sB[16], sC[16];
  if(tid < 16) sB[tid] = BmCm[(size_t)b*32 + tid];
  else if(tid < 32) sC[tid-16] = BmCm[(size_t)b*32 + tid];
  __syncthreads();
  #pragma unroll
  for(int it=0; it<8; ++it){
    const int d = it*64 + (tid >> 2);
    const float dl = delta[(size_t)b*Dn + d];
    const float xc = __bfloat162float(xconv[(size_t)b*Dn + d]);
    const size_t off = ((size_t)b*Dn + d)*Sn + qlane*4;
    f32x4 st = *(const f32x4*)(state + off);
    f32x4 Av = *(const f32x4*)(A + d*Sn + qlane*4);
    f32x4 ns;
    float xs = 0.f;
    #pragma unroll
    for(int j=0;j<4;j++){
      const int s = qlane*4 + j;
      const float da = __expf(dl * Av[j]);
      const float nv = st[j]*da + dl*sB[s]*xc;
      ns[j] = nv;
      xs += nv * sC[s];
    }
    *(f32x4*)(nstate + off) = ns;
    xs += __shfl_xor(xs, 1);
    xs += __shfl_xor(xs, 2);
    if(qlane == 0){
      const float vv = __bfloat162float(vbuf[(size_t)b*Dn + d]);
      gbuf[(size_t)b*Dn + d] = __float2bfloat16(xs * vv);
    }
  }
}

extern "C" void kernel_launch(void* const* d_in, const int* in_sizes, int n_in,
                              void* d_out, int out_size, void* d_ws, size_t ws_size,
                              hipStream_t stream)
{
  const float* x      = (const float*)d_in[0];
  const float* sst    = (const float*)d_in[1];
  const float* ln_g   = (const float*)d_in[2];
  const float* ln_b   = (const float*)d_in[3];
  const float* w1_W   = (const float*)d_in[4];
  const float* w1_b   = (const float*)d_in[5];
  const float* v1_W   = (const float*)d_in[6];
  const float* v1_b   = (const float*)d_in[7];
  const float* w2_W   = (const float*)d_in[8];
  const float* w2_b   = (const float*)d_in[9];
  const float* conv_w = (const float*)d_in[10];
  const float* A_log  = (const float*)d_in[11];
  const float* Bp_W   = (const float*)d_in[12];
  const float* Bp_b   = (const float*)d_in[13];
  const float* Cp_W   = (const float*)d_in[14];
  const float* Cp_b   = (const float*)d_in[15];
  const float* dt_W   = (const float*)d_in[16];
  const float* dt_b   = (const float*)d_in[17];

  float* out    = (float*)d_out;
  float* nstate = out + (size_t)Bn*Dn;

  char* wsp = (char*)d_ws;
  auto alloc = [&](size_t bytes)->char*{
    char* p = wsp; wsp += (bytes + 255) & ~(size_t)255; return p;
  };
  __hip_bfloat16* xnorm = (__hip_bfloat16*)alloc((size_t)Bn*Dn*2);
  __hip_bfloat16* xconv = (__hip_bfloat16*)alloc((size_t)Bn*Dn*2);
  __hip_bfloat16* vbuf  = (__hip_bfloat16*)alloc((size_t)Bn*Dn*2);
  __hip_bfloat16* gbuf  = (__hip_bfloat16*)alloc((size_t)Bn*Dn*2);
  float*          delta = (float*)alloc((size_t)Bn*Dn*4);
  __hip_bfloat16* w1b   = (__hip_bfloat16*)alloc((size_t)Dn*Dn*2);
  __hip_bfloat16* v1b   = (__hip_bfloat16*)alloc((size_t)Dn*Dn*2);
  __hip_bfloat16* dtb   = (__hip_bfloat16*)alloc((size_t)Dn*Dn*2);
  __hip_bfloat16* w2b   = (__hip_bfloat16*)alloc((size_t)Dn*Dn*2);
  __hip_bfloat16* bpcpb = (__hip_bfloat16*)alloc((size_t)2*Sn*Dn*2);
  float*          BmCm  = (float*)alloc((size_t)Bn*32*4);
  float*          Abuf  = (float*)alloc((size_t)Dn*Sn*4);

  // 1. prep
  prep_kernel<<<dim3(Dn*Dn/256), dim3(256), 0, stream>>>(
      w1_W, v1_W, dt_W, w2_W, Bp_W, Cp_W, A_log, w1b, v1b, dtb, w2b, bpcpb, Abuf);
  // 2. layernorm
  ln_kernel<<<dim3(Bn/4), dim3(256), 0, stream>>>(x, ln_g, ln_b, xnorm);
  // 3+4. fused: x_conv = silu((x_norm@w1^T + b)*cw), v = silu(x_norm@v1^T + b)
  tgemm_kernel<1,2,true,false,true><<<dim3(Dn/64, Bn/128), dim3(256), 0, stream>>>(
      xnorm, w1b, v1b, nullptr, w1_b, v1_b, nullptr, nullptr, conv_w,
      (void*)xconv, (void*)vbuf, nullptr, Bn, Dn, Dn);
  // 5. delta = softplus(x_conv@dt^T + b) (fp32) + fused Bm/Cm (blockIdx.x==0)
  tgemm_kernel<3,0,false,true,false><<<dim3(Dn/64, Bn/128), dim3(256), 0, stream>>>(
      xconv, dtb, nullptr, bpcpb, dt_b, nullptr, Bp_b, Cp_b, nullptr,
      (void*)delta, nullptr, BmCm, Bn, Dn, Dn);
  // 6. SSM elementwise + g
  ssm_kernel<<<dim3(Bn), dim3(256), 0, stream>>>(
      sst, delta, xconv, vbuf, BmCm, Abuf, nstate, gbuf);
  // 7. out = g@w2^T + b (fp32)
  tgemm_kernel<0,0,false,false,false><<<dim3(Dn/64, Bn/128), dim3(256), 0, stream>>>(
      gbuf, w2b, nullptr, nullptr, w2_b, nullptr, nullptr, nullptr, nullptr,
      (void*)out, nullptr, nullptr, Bn, Dn, Dn);
}

// Round 4
// 178.113 us; speedup vs baseline: 1.5901x; 1.0426x over previous
//
#include <hip/hip_runtime.h>
#include <hip/hip_bf16.h>
#include <cstdint>
#include <cstddef>

#define Bn 8192
#define Dn 512
#define Sn 16

typedef __attribute__((ext_vector_type(4))) float f32x4;
typedef __attribute__((ext_vector_type(8))) __bf16 bf16x8;
typedef __attribute__((ext_vector_type(8))) short short8;

union BF8 { short8 s; __hip_bfloat16 h[8]; };

__device__ __forceinline__ void gload16(const void* gsrc, void* ldst){
  __builtin_amdgcn_global_load_lds(
      (const __attribute__((address_space(1))) void*)gsrc,
      (__attribute__((address_space(3))) void*)ldst, 16, 0, 0);
}

// ---------- prep: cast weights to bf16, compute A = -exp(A_log) ----------
__global__ __launch_bounds__(256) void prep_kernel(
    const float* __restrict__ w1, const float* __restrict__ v1,
    const float* __restrict__ dt, const float* __restrict__ w2,
    const float* __restrict__ Bp, const float* __restrict__ Cp,
    const float* __restrict__ Alog,
    __hip_bfloat16* __restrict__ w1b, __hip_bfloat16* __restrict__ v1b,
    __hip_bfloat16* __restrict__ dtb, __hip_bfloat16* __restrict__ w2b,
    __hip_bfloat16* __restrict__ bpcpb, float* __restrict__ A)
{
  int i = blockIdx.x*256 + threadIdx.x;
  if(i < Dn*Dn){
    w1b[i] = __float2bfloat16(w1[i]);
    v1b[i] = __float2bfloat16(v1[i]);
    dtb[i] = __float2bfloat16(dt[i]);
    w2b[i] = __float2bfloat16(w2[i]);
  }
  if(i < Sn*Dn){
    bpcpb[i]         = __float2bfloat16(Bp[i]);
    bpcpb[Sn*Dn + i] = __float2bfloat16(Cp[i]);
  }
  if(i < Dn*Sn){
    A[i] = -expf(Alog[i]);
  }
}

// ---------- LayerNorm: fp32 in -> bf16 out, one wave per row ----------
__global__ __launch_bounds__(256) void ln_kernel(
    const float* __restrict__ x, const float* __restrict__ g,
    const float* __restrict__ bta, __hip_bfloat16* __restrict__ xn)
{
  const int lane = threadIdx.x & 63;
  const int row  = blockIdx.x*4 + (threadIdx.x >> 6);
  const float* xr = x + (size_t)row*Dn;
  const int c = lane*8;
  f32x4 a0 = *(const f32x4*)(xr + c);
  f32x4 a1 = *(const f32x4*)(xr + c + 4);
  float s = 0.f, q = 0.f;
  #pragma unroll
  for(int j=0;j<4;j++){ s += a0[j]+a1[j]; q += a0[j]*a0[j] + a1[j]*a1[j]; }
  #pragma unroll
  for(int off=32; off; off >>= 1){ s += __shfl_xor(s, off); q += __shfl_xor(q, off); }
  const float mu = s * (1.f/Dn);
  const float rs = rsqrtf(q*(1.f/Dn) - mu*mu + 1e-5f);
  f32x4 g0 = *(const f32x4*)(g + c);
  f32x4 g1 = *(const f32x4*)(g + c + 4);
  f32x4 b0 = *(const f32x4*)(bta + c);
  f32x4 b1 = *(const f32x4*)(bta + c + 4);
  BF8 o;
  #pragma unroll
  for(int j=0;j<4;j++){
    o.h[j]   = __float2bfloat16((a0[j]-mu)*rs*g0[j] + b0[j]);
    o.h[4+j] = __float2bfloat16((a1[j]-mu)*rs*g1[j] + b1[j]);
  }
  *(short8*)(xn + (size_t)row*Dn + c) = o.s;
}

// ---------- tiled MFMA GEMM, race-free counted 2-deep pipeline + XCD swizzle --
// C[M,N] = act(X[M,K] @ W[N,K]^T + bias)
// DUAL: second weight W2 sharing the A-tile (w1+v1 fusion)
// BC:   third tiny weight W3 [32,K] computed by tile_x==0 blocks (Bm/Cm fusion)
// Tile: BM=128, BN=64, BK=64, 256 threads.
// Schedule per iter t: STAGE(t+1 -> buf^1) ; vmcnt(L) [drains t] ; ds_read t ;
//   MFMA ; s_barrier.  End-of-iter barrier makes top-of-next STAGE safe
//   (each wave's MFMA implies its ds_reads of that buffer completed).
// ACT: 0=none, 1=silu(y*convw_center), 2=silu(y), 3=softplus(y)
template<int ACT1, int ACT2, bool DUAL, bool BC, bool OBF>
__global__ __launch_bounds__(256) void tgemm_kernel(
    const __hip_bfloat16* __restrict__ X,
    const __hip_bfloat16* __restrict__ W1,
    const __hip_bfloat16* __restrict__ W2,
    const __hip_bfloat16* __restrict__ W3,
    const float* __restrict__ bias1,
    const float* __restrict__ bias2,
    const float* __restrict__ bpb,
    const float* __restrict__ cpb,
    const float* __restrict__ convw,
    void* __restrict__ out1, void* __restrict__ out2,
    float* __restrict__ out3,
    int M, int N, int K)
{
  constexpr int AB  = 16384;                 // A tile bytes: 128 x 64 bf16
  constexpr int B1B = 8192;                  // B tile: 64 x 64 bf16
  constexpr int B2O = AB + B1B;
  constexpr int B3O = B2O + (DUAL ? 8192 : 0);
  constexpr int BUFSZ = B3O + (BC ? 4096 : 0);
  __shared__ char smem[2*BUFSZ] __attribute__((aligned(128)));

  const int tid  = threadIdx.x;
  const int wv   = tid >> 6;
  const int lane = tid & 63;

  // XCD-aware bijective remap: hw-linear id r (x fastest, r%8 = XCD) ->
  // tile o so each XCD owns a contiguous slab of row-panels (A reuse in L2).
  const int r    = blockIdx.x + blockIdx.y*gridDim.x;
  const int q    = (gridDim.x*gridDim.y) >> 3;     // blocks per XCD (grid%8==0)
  const int o    = (r & 7)*q + (r >> 3);
  const int tx   = o % gridDim.x;
  const int ty   = o / gridDim.x;
  const int r0 = ty * 128;
  const int c0 = tx * 64;
  const bool doBC = BC && (tx == 0);

  f32x4 acc1[4][2] = {};
  f32x4 acc2[4][2] = {};
  f32x4 acc3[4]    = {};

  const int lr = lane & 15;
  const int lg = lane >> 4;

  auto stage = [&](int buf, int kk){
    char* base = smem + buf*BUFSZ;
    #pragma unroll
    for(int i=0;i<4;i++){
      const int off = i*4096 + tid*16;
      const int row = off >> 7;
      const int g   = ((off>>4)&7) ^ (row&7);
      gload16(X + (size_t)(r0+row)*K + kk + g*8, base + i*4096 + (wv<<10));
    }
    #pragma unroll
    for(int i=0;i<2;i++){
      const int off = i*4096 + tid*16;
      const int row = off >> 7;
      const int g   = ((off>>4)&7) ^ (row&7);
      gload16(W1 + (size_t)(c0+row)*K + kk + g*8, base + AB + i*4096 + (wv<<10));
      if(DUAL)
        gload16(W2 + (size_t)(c0+row)*K + kk + g*8, base + B2O + i*4096 + (wv<<10));
    }
    if(BC){ if(doBC){
      const int off = tid*16;
      const int row = off >> 7;
      const int g   = ((off>>4)&7) ^ (row&7);
      gload16(W3 + (size_t)row*K + kk + g*8, base + B3O + (wv<<10));
    }}
  };

  const int NT = K >> 6;
  stage(0, 0);
  for(int t=0; t<NT; ++t){
    const int cur = t & 1;
    if(t+1 < NT){
      stage(cur^1, (t+1)<<6);
      // drain only tile t's loads (FIFO); leave t+1's in flight
      if constexpr (DUAL){
        asm volatile("s_waitcnt vmcnt(8)" ::: "memory");
      } else if constexpr (BC){
        if(doBC) asm volatile("s_waitcnt vmcnt(7)" ::: "memory");
        else     asm volatile("s_waitcnt vmcnt(6)" ::: "memory");
      } else {
        asm volatile("s_waitcnt vmcnt(6)" ::: "memory");
      }
    } else {
      asm volatile("s_waitcnt vmcnt(0)" ::: "memory");
    }

    const char* base = smem + cur*BUFSZ;
    bf16x8 af[4][2], b1f[2][2], b2f[2][2], b3f[2];
    #pragma unroll
    for(int m=0;m<4;m++){
      #pragma unroll
      for(int k2=0;k2<2;k2++){
        const int rr = (wv>>1)*64 + m*16 + lr;
        const int cc = (k2*4 + lg) ^ (rr&7);
        af[m][k2] = *(const bf16x8*)(base + rr*128 + cc*16);
      }
    }
    #pragma unroll
    for(int n=0;n<2;n++){
      #pragma unroll
      for(int k2=0;k2<2;k2++){
        const int rr = (wv&1)*32 + n*16 + lr;
        const int cc = (k2*4 + lg) ^ (rr&7);
        b1f[n][k2] = *(const bf16x8*)(base + AB + rr*128 + cc*16);
        if(DUAL)
          b2f[n][k2] = *(const bf16x8*)(base + B2O + rr*128 + cc*16);
      }
    }
    if(BC){ if(doBC){
      #pragma unroll
      for(int k2=0;k2<2;k2++){
        const int rr = (wv&1)*16 + lr;
        const int cc = (k2*4 + lg) ^ (rr&7);
        b3f[k2] = *(const bf16x8*)(base + B3O + rr*128 + cc*16);
      }
    }}

    #pragma unroll
    for(int k2=0;k2<2;k2++){
      #pragma unroll
      for(int m=0;m<4;m++){
        #pragma unroll
        for(int n=0;n<2;n++){
          acc1[m][n] = __builtin_amdgcn_mfma_f32_16x16x32_bf16(af[m][k2], b1f[n][k2], acc1[m][n], 0, 0, 0);
          if(DUAL)
            acc2[m][n] = __builtin_amdgcn_mfma_f32_16x16x32_bf16(af[m][k2], b2f[n][k2], acc2[m][n], 0, 0, 0);
        }
        if(BC){ if(doBC){
          acc3[m] = __builtin_amdgcn_mfma_f32_16x16x32_bf16(af[m][k2], b3f[k2], acc3[m], 0, 0, 0);
        }}
      }
    }
    if(t+1 < NT) __builtin_amdgcn_s_barrier();
  }

  const int er = lg*4;
  const int ec = lr;
  #pragma unroll
  for(int n=0;n<2;n++){
    const int cc = c0 + (wv&1)*32 + n*16 + ec;
    const float bv1 = bias1[cc];
    const float cwv = (ACT1==1) ? convw[cc*3+1] : 0.f;
    const float bv2 = DUAL ? bias2[cc] : 0.f;
    #pragma unroll
    for(int m=0;m<4;m++){
      #pragma unroll
      for(int j=0;j<4;j++){
        const int rr = r0 + (wv>>1)*64 + m*16 + er + j;
        float y = acc1[m][n][j] + bv1;
        if(ACT1==1){ float z = y*cwv; y = z/(1.f + __expf(-z)); }
        if(ACT1==2){ y = y/(1.f + __expf(-y)); }
        if(ACT1==3){ y = (y > 20.f) ? y : log1pf(__expf(y)); }
        if(OBF) ((__hip_bfloat16*)out1)[(size_t)rr*N + cc] = __float2bfloat16(y);
        else    ((float*)out1)[(size_t)rr*N + cc] = y;
        if(DUAL){
          float y2 = acc2[m][n][j] + bv2;
          if(ACT2==1){ float z = y2*cwv; y2 = z/(1.f + __expf(-z)); }
          if(ACT2==2){ y2 = y2/(1.f + __expf(-y2)); }
          if(ACT2==3){ y2 = (y2 > 20.f) ? y2 : log1pf(__expf(y2)); }
          if(OBF) ((__hip_bfloat16*)out2)[(size_t)rr*N + cc] = __float2bfloat16(y2);
          else    ((float*)out2)[(size_t)rr*N + cc] = y2;
        }
      }
    }
  }
  if(BC){ if(doBC){
    const int cc3 = (wv&1)*16 + ec;
    const float bv3 = (cc3 < 16) ? bpb[cc3] : cpb[cc3-16];
    #pragma unroll
    for(int m=0;m<4;m++){
      #pragma unroll
      for(int j=0;j<4;j++){
        const int rr = r0 + (wv>>1)*64 + m*16 + er + j;
        out3[(size_t)rr*32 + cc3] = acc3[m][j] + bv3;
      }
    }
  }}
}

// ---------- SSM elementwise: next_state + g = x_ssm*v ----------
__global__ __launch_bounds__(256) void ssm_kernel(
    const float* __restrict__ state,
    const __hip_bfloat16* __restrict__ delta,
    const __hip_bfloat16* __restrict__ xconv,
    const __hip_bfloat16* __restrict__ vbuf,
    const float* __restrict__ BmCm,
    const float* __restrict__ A,
    float* __restrict__ nstate,
    __hip_bfloat16* __restrict__ gbuf)
{
  const int b = blockIdx.x;
  const int tid = threadIdx.x;
  const int qlane = tid & 3;
  __shared__ float sB[16], sC[16];
  if(tid < 16) sB[tid] = BmCm[(size_t)b*32 + tid];
  else if(tid < 32) sC[tid-16] = BmCm[(size_t)b*32 + tid];
  __syncthreads();
  #pragma unroll
  for(int it=0; it<8; ++it){
    const int d = it*64 + (tid >> 2);
    const float dl = __bfloat162float(delta[(size_t)b*Dn + d]);
    const float xc = __bfloat162float(xconv[(size_t)b*Dn + d]);
    const size_t off = ((size_t)b*Dn + d)*Sn + qlane*4;
    f32x4 st = *(const f32x4*)(state + off);
    f32x4 Av = *(const f32x4*)(A + d*Sn + qlane*4);
    f32x4 ns;
    float xs = 0.f;
    #pragma unroll
    for(int j=0;j<4;j++){
      const int s = qlane*4 + j;
      const float da = __expf(dl * Av[j]);
      const float nv = st[j]*da + dl*sB[s]*xc;
      ns[j] = nv;
      xs += nv * sC[s];
    }
    *(f32x4*)(nstate + off) = ns;
    xs += __shfl_xor(xs, 1);
    xs += __shfl_xor(xs, 2);
    if(qlane == 0){
      const float vv = __bfloat162float(vbuf[(size_t)b*Dn + d]);
      gbuf[(size_t)b*Dn + d] = __float2bfloat16(xs * vv);
    }
  }
}

extern "C" void kernel_launch(void* const* d_in, const int* in_sizes, int n_in,
                              void* d_out, int out_size, void* d_ws, size_t ws_size,
                              hipStream_t stream)
{
  const float* x      = (const float*)d_in[0];
  const float* sst    = (const float*)d_in[1];
  const float* ln_g   = (const float*)d_in[2];
  const float* ln_b   = (const float*)d_in[3];
  const float* w1_W   = (const float*)d_in[4];
  const float* w1_b   = (const float*)d_in[5];
  const float* v1_W   = (const float*)d_in[6];
  const float* v1_b   = (const float*)d_in[7];
  const float* w2_W   = (const float*)d_in[8];
  const float* w2_b   = (const float*)d_in[9];
  const float* conv_w = (const float*)d_in[10];
  const float* A_log  = (const float*)d_in[11];
  const float* Bp_W   = (const float*)d_in[12];
  const float* Bp_b   = (const float*)d_in[13];
  const float* Cp_W   = (const float*)d_in[14];
  const float* Cp_b   = (const float*)d_in[15];
  const float* dt_W   = (const float*)d_in[16];
  const float* dt_b   = (const float*)d_in[17];

  float* out    = (float*)d_out;
  float* nstate = out + (size_t)Bn*Dn;

  char* wsp = (char*)d_ws;
  auto alloc = [&](size_t bytes)->char*{
    char* p = wsp; wsp += (bytes + 255) & ~(size_t)255; return p;
  };
  __hip_bfloat16* xnorm = (__hip_bfloat16*)alloc((size_t)Bn*Dn*2);
  __hip_bfloat16* xconv = (__hip_bfloat16*)alloc((size_t)Bn*Dn*2);
  __hip_bfloat16* vbuf  = (__hip_bfloat16*)alloc((size_t)Bn*Dn*2);
  __hip_bfloat16* gbuf  = (__hip_bfloat16*)alloc((size_t)Bn*Dn*2);
  __hip_bfloat16* delta = (__hip_bfloat16*)alloc((size_t)Bn*Dn*2);
  __hip_bfloat16* w1b   = (__hip_bfloat16*)alloc((size_t)Dn*Dn*2);
  __hip_bfloat16* v1b   = (__hip_bfloat16*)alloc((size_t)Dn*Dn*2);
  __hip_bfloat16* dtb   = (__hip_bfloat16*)alloc((size_t)Dn*Dn*2);
  __hip_bfloat16* w2b   = (__hip_bfloat16*)alloc((size_t)Dn*Dn*2);
  __hip_bfloat16* bpcpb = (__hip_bfloat16*)alloc((size_t)2*Sn*Dn*2);
  float*          BmCm  = (float*)alloc((size_t)Bn*32*4);
  float*          Abuf  = (float*)alloc((size_t)Dn*Sn*4);

  // 1. prep
  prep_kernel<<<dim3(Dn*Dn/256), dim3(256), 0, stream>>>(
      w1_W, v1_W, dt_W, w2_W, Bp_W, Cp_W, A_log, w1b, v1b, dtb, w2b, bpcpb, Abuf);
  // 2. layernorm
  ln_kernel<<<dim3(Bn/4), dim3(256), 0, stream>>>(x, ln_g, ln_b, xnorm);
  // 3+4. fused: x_conv = silu((x_norm@w1^T + b)*cw), v = silu(x_norm@v1^T + b)
  tgemm_kernel<1,2,true,false,true><<<dim3(Dn/64, Bn/128), dim3(256), 0, stream>>>(
      xnorm, w1b, v1b, nullptr, w1_b, v1_b, nullptr, nullptr, conv_w,
      (void*)xconv, (void*)vbuf, nullptr, Bn, Dn, Dn);
  // 5. delta = softplus(x_conv@dt^T + b) (bf16) + fused Bm/Cm (tile_x==0)
  tgemm_kernel<3,0,false,true,true><<<dim3(Dn/64, Bn/128), dim3(256), 0, stream>>>(
      xconv, dtb, nullptr, bpcpb, dt_b, nullptr, Bp_b, Cp_b, nullptr,
      (void*)delta, nullptr, BmCm, Bn, Dn, Dn);
  // 6. SSM elementwise + g
  ssm_kernel<<<dim3(Bn), dim3(256), 0, stream>>>(
      sst, delta, xconv, vbuf, BmCm, Abuf, nstate, gbuf);
  // 7. out = g@w2^T + b (fp32)
  tgemm_kernel<0,0,false,false,false><<<dim3(Dn/64, Bn/128), dim3(256), 0, stream>>>(
      gbuf, w2b, nullptr, nullptr, w2_b, nullptr, nullptr, nullptr, nullptr,
      (void*)out, nullptr, nullptr, Bn, Dn, Dn);
}